// Round 12
// baseline (194.965 us; speedup 1.0000x reference)
//
#include <hip/hip_runtime.h>

typedef unsigned short ushort_t;
typedef unsigned int uint_t;
typedef __attribute__((ext_vector_type(8))) _Float16 f16x8;
typedef __attribute__((ext_vector_type(4))) _Float16 f16x4;
typedef __attribute__((ext_vector_type(2))) _Float16 f16x2;
typedef __attribute__((ext_vector_type(4))) float floatx4;

#define ZDIM 32
#define KDIM 4
#define HDIM 128
#define B_TOTAL 32768
#define TB 64

// ws layout (ushort element offsets): Wd fp16 [k][n][c], Wsm fp16 [m][n][c]
#define WS_WD16 0            // 4*1024*128 = 524288
#define WS_SM16 524288       // 3*128*128 = 49152

// LDS layout: identical to rounds 6/8/10 (TB=64, D fp16 [i][j][b64+4pad]).
// Round-24 change vs round-10: pure VALU-issue trim, no structural change.
//  (a) bias folded into the MFMA accumulator (D = A*B + C with C = bias):
//      removes 16 v_add_f32 per g-iter (512/thread/slot) + aux-GEMM adds.
//  (b) v_cvt_pkrtz_f16_f32 for ALL f32->f16 stores (D, t, aux packs, h
//      staging): 1 instr / 2 values vs cvt-per-value (+shifts in packs).
//  (RTZ vs RTE: <=1 ulp fp16 on intermediates; absmax headroom is ample.)
// Bank note: pair-granularity analysis (byte/8 mod 16) shows D/t/z reads
// already distribute 4 lanes/slot = optimal; the 4.4M conflict counter is
// not the naive even-bank story, so the layout stays (also 8-B-align-
// constrained: D_PJ halves must be %4==0).
#define D_PJ 68              // halves; j stride = 64 batches + 4 pad
#define D_BI 2180            // halves; i stride = 32*68+4
#define SH_D_OFF 0           // 32*2180*2 = 139520 B
#define AUX_PITCH 132
#define AUX_MS (64 * AUX_PITCH)
#define SH_AUX_OFF 0         // float [3][64][132] = 101376 B (pre-loop, aliases D)
#define SH_H_OFF 101376      // half [64][136] = 17408 B (pre-loop, aliases D; ends 118784)
#define SH_ZT_OFF 139520     // float z^T [32][68] = 8704 B (ends 148224)
#define SH_TT_OFF 148224     // half t^T [32][68] = 4352 B (ends 152576)
#define LDS_BYTES 152576     // 1 WG/CU (<= 163840)

__device__ __forceinline__ float fast_tanh(float x) {
    float e = __expf(2.0f * x);
    return 1.0f - 2.0f / (e + 1.0f);
}
__device__ __forceinline__ float f16lo(uint_t v) {
    return (float)__builtin_bit_cast(_Float16, (ushort_t)(v & 0xFFFFu));
}
__device__ __forceinline__ float f16hi(uint_t v) {
    return (float)__builtin_bit_cast(_Float16, (ushort_t)(v >> 16));
}
// pack 2 f32 -> 1 dword of fp16 via v_cvt_pkrtz_f16_f32 (1 VALU op)
__device__ __forceinline__ uint_t pk2(float a, float b) {
    return __builtin_bit_cast(uint_t, __builtin_amdgcn_cvt_pkrtz(a, b));
}
__device__ __forceinline__ ushort4 cvt4(float4 v) {
    uint_t lo = pk2(v.x, v.y), hi = pk2(v.z, v.w);
    ushort4 o;
    o.x = (ushort_t)(lo & 0xFFFFu); o.y = (ushort_t)(lo >> 16);
    o.z = (ushort_t)(hi & 0xFFFFu); o.w = (ushort_t)(hi >> 16);
    return o;
}
// pack 4 floats into 2 dwords of fp16
__device__ __forceinline__ uint2 packq(const float* p) {
    uint2 r;
    r.x = pk2(p[0], p[1]);
    r.y = pk2(p[2], p[3]);
    return r;
}
// runtime-kk variant: kk is wave-uniform -> s_cselect + cndmask, cheap
__device__ __forceinline__ float half_at(uint2 q, int kk) {
    uint_t w = (kk & 2) ? q.y : q.x;
    return (kk & 1) ? f16hi(w) : f16lo(w);
}

// ---- v_fma_mix_f32 helpers: acc += f16(a,half) * b  (b = f32 or f16) ----
__device__ __forceinline__ void fmix_lo(float& acc, uint_t a, float b) {
    asm("v_fma_mix_f32 %0, %1, %2, %0 op_sel_hi:[1,0,0]"
        : "+v"(acc) : "v"(a), "v"(b));
}
__device__ __forceinline__ void fmix_hi(float& acc, uint_t a, float b) {
    asm("v_fma_mix_f32 %0, %1, %2, %0 op_sel:[1,0,0] op_sel_hi:[1,0,0]"
        : "+v"(acc) : "v"(a), "v"(b));
}
__device__ __forceinline__ void fmix2_ll(float& acc, uint_t a, uint_t b) {
    asm("v_fma_mix_f32 %0, %1, %2, %0 op_sel_hi:[1,1,0]"
        : "+v"(acc) : "v"(a), "v"(b));
}
__device__ __forceinline__ void fmix2_hh(float& acc, uint_t a, uint_t b) {
    asm("v_fma_mix_f32 %0, %1, %2, %0 op_sel:[1,1,0] op_sel_hi:[1,1,0]"
        : "+v"(acc) : "v"(a), "v"(b));
}

// ---------------------------------------------------------------------------
// Kernel 1: convert Wd (reordered per-k-slice) and Wd1/Wd2/Wb to fp16.
// ---------------------------------------------------------------------------
__global__ __launch_bounds__(256) void convert_kernel(
    const float* __restrict__ Wd, const float* __restrict__ Wd1,
    const float* __restrict__ Wd2, const float* __restrict__ Wb,
    ushort_t* __restrict__ ws)
{
    int g = blockIdx.x * 256 + threadIdx.x;
    if (g < 131072) {
        int k = g >> 15;            // 32768 float4 per k-slice
        int rem = g & 32767;
        int n = rem >> 5;           // n = i*32+j
        int c4 = rem & 31;
        float4 v = *((const float4*)Wd + (size_t)(4 * n + k) * 32 + c4);
        ((ushort4*)(ws + WS_WD16))[g] = cvt4(v);
    } else {
        int s = g - 131072;         // [0, 12288)
        const float* src = (s < 4096) ? Wd1 : ((s < 8192) ? Wd2 : Wb);
        int r = s & 4095;
        float4 v = ((const float4*)src)[r];
        ((ushort4*)(ws + WS_SM16))[s] = cvt4(v);
    }
}

// ---------------------------------------------------------------------------
// Kernel 2: fused fp16 encoder GEMMs + K-step flow. TB=64 batches/WG,
// 512 threads (8 waves), 1 WG/CU, 512 WGs (2 slots/CU). GEMM identical
// to rounds 6/8/10 except bias-in-acc + pkrtz stores. Flow mapping:
// fj = t>>4 (wave-clustered), fg = t&15. 3 barriers per k.
// ---------------------------------------------------------------------------
__global__ __launch_bounds__(512, 2) void sylv_kernel(
    const ushort_t* __restrict__ wsb,
    const float* __restrict__ hglob,
    const float* __restrict__ z0,
    const float* __restrict__ bd,
    const float* __restrict__ bd1,
    const float* __restrict__ bd2,
    const float* __restrict__ bb,
    float* __restrict__ out)
{
    extern __shared__ char smem[];
    _Float16* Dh     = (_Float16*)(smem + SH_D_OFF);
    float*    sh_aux = (float*)(smem + SH_AUX_OFF);
    _Float16* sh_h   = (_Float16*)(smem + SH_H_OFF);
    float*    sh_zt  = (float*)(smem + SH_ZT_OFF);
    _Float16* Th     = (_Float16*)(smem + SH_TT_OFF);

    const int t   = threadIdx.x;
    const int bg0 = blockIdx.x * TB;
    const int lane = t & 63, w = t >> 6;    // w = 0..7 = GEMM column group
    const int l15 = lane & 15, l4 = lane >> 4;
    // flow mapping: fj = row/col index (wave-clustered), fg = 4-batch group
    const int fj = t >> 4;          // 0..31; wave w covers fj in [4w, 4w+3]
    const int fg = t & 15;          // 0..15
    const int fjc = w * 4;          // wave-uniform cluster base

    // ---- stage h (fp32 -> fp16 in LDS) and z0 transposed ----
    {
        const float4* hsrc = (const float4*)(hglob + (size_t)bg0 * HDIM);
        #pragma unroll
        for (int it = 0; it < 4; ++it) {
            int c = t + it * 512;       // 2048 float4 chunks (64 rows x 32)
            int row = c >> 5, col4 = c & 31;
            float4 v = hsrc[c];
            *(ushort4*)((ushort_t*)sh_h + row * 136 + col4 * 4) = cvt4(v);
        }
        int zb = t >> 3;                // 0..63 (batch)
        int zi0 = (t & 7) * 4;          // i index
        float4 zv = *(const float4*)(z0 + (size_t)(bg0 + zb) * ZDIM + zi0);
        sh_zt[(zi0 + 0) * 68 + zb] = zv.x;
        sh_zt[(zi0 + 1) * 68 + zb] = zv.y;
        sh_zt[(zi0 + 2) * 68 + zb] = zv.z;
        sh_zt[(zi0 + 3) * 68 + zb] = zv.w;
    }
    __syncthreads();

    // ---- A fragments: FOUR 16-row tiles (rows 0..63), same for all waves ----
    f16x8 ah[4][4];
    #pragma unroll
    for (int mt = 0; mt < 4; ++mt)
        #pragma unroll
        for (int kc = 0; kc < 4; ++kc)
            ah[mt][kc] = *(const f16x8*)(sh_h + (mt * 16 + l15) * 136 + kc * 32 + l4 * 8);

    // ---- small GEMMs (fp16): d1, d2, bpre -> aux[m][batch][n] ----
    #pragma unroll 1
    for (int pi = 0; pi < 3; ++pi) {
        int p = w * 3 + pi;             // [0,24)
        int m_i = p >> 3, nt = p & 7, n = nt * 16 + l15;
        const _Float16* wp = (const _Float16*)(wsb + WS_SM16) + (size_t)(m_i * 128 + n) * 128 + l4 * 8;
        const float* bv = (m_i == 0) ? bd1 : ((m_i == 1) ? bd2 : bb);
        float bias = bv[n];
        floatx4 a[4];
        #pragma unroll
        for (int mt = 0; mt < 4; ++mt)
            a[mt] = (floatx4){bias, bias, bias, bias};
        #pragma unroll
        for (int kc = 0; kc < 4; ++kc) {
            f16x8 bh = *(const f16x8*)(wp + kc * 32);
            #pragma unroll
            for (int mt = 0; mt < 4; ++mt)
                a[mt] = __builtin_amdgcn_mfma_f32_16x16x32_f16(ah[mt][kc], bh, a[mt], 0, 0, 0);
        }
        float* ap = sh_aux + m_i * AUX_MS + n;
        #pragma unroll
        for (int mt = 0; mt < 4; ++mt) {
            #pragma unroll
            for (int r = 0; r < 4; ++r) {
                float v0 = a[mt][r];
                if (m_i < 2) v0 = fast_tanh(v0);
                ap[(mt * 16 + l4 * 4 + r) * AUX_PITCH] = v0;
            }
        }
    }
    __syncthreads();

    // ---- pack aux for (fj, 4 batches) x 4 k into fp16 regs ----
    uint2 d1q[4], d2q[4], bpq[4];
    {
        #pragma unroll
        for (int e = 0; e < 4; ++e) {
            const float* base = sh_aux + (4 * fg + e) * AUX_PITCH + 4 * fj;
            d1q[e] = packq(base + 0 * AUX_MS);
            d2q[e] = packq(base + 1 * AUX_MS);
            bpq[e] = packq(base + 2 * AUX_MS);
        }
    }
    __syncthreads();

    float ld4[4] = {1.f, 1.f, 1.f, 1.f};    // product of dj per (row, batch)

    #pragma unroll 1
    for (int kk = 0; kk < KDIM; ++kk) {
        // ---- GEMM: D_k[b][n] = h@Wd_k^T + bd; write [i][j][b] as b64 ----
        const _Float16* wdk = (const _Float16*)(wsb + WS_WD16) + (size_t)kk * 131072;
        #pragma unroll 2
        for (int g = 0; g < 8; ++g) {
            int nc = w * 128 + g * 16 + l15;
            const _Float16* w0 = wdk + (size_t)nc * 128 + l4 * 8;
            float bias0 = bd[4 * nc + kk];
            floatx4 a[4];
            #pragma unroll
            for (int mt = 0; mt < 4; ++mt)
                a[mt] = (floatx4){bias0, bias0, bias0, bias0};
            #pragma unroll
            for (int kc = 0; kc < 4; ++kc) {
                f16x8 b0 = *(const f16x8*)(w0 + kc * 32);
                #pragma unroll
                for (int mt = 0; mt < 4; ++mt)
                    a[mt] = __builtin_amdgcn_mfma_f32_16x16x32_f16(ah[mt][kc], b0, a[mt], 0, 0, 0);
            }
            int ii = nc >> 5, jj = nc & 31;
            int base = ii * D_BI + jj * D_PJ;       // halves
            #pragma unroll
            for (int mt = 0; mt < 4; ++mt) {
                uint2 ov;
                ov.x = pk2(a[mt][0], a[mt][1]);
                ov.y = pk2(a[mt][2], a[mt][3]);
                *(uint2*)(Dh + base + mt * 16 + l4 * 4) = ov;  // batches mt*16+l4*4..+3
            }
        }
        __syncthreads();

        const bool flip = (kk & 1) != 0;
        const int zr_j = flip ? (31 - fj) : fj;
        float tq4[4];
        {
            // ---- pre[j][b] = bp + z_per[j]*d2 + sum_{i>j} z_per[i]*D[i,j,b] ----
            float s4[4];
            {
                floatx4 zj = *(const floatx4*)(sh_zt + zr_j * 68 + 4 * fg);
                #pragma unroll
                for (int e = 0; e < 4; ++e)
                    s4[e] = half_at(bpq[e], kk) + zj[e] * half_at(d2q[e], kk);
            }
            // boundary iters i = fjc+1..fjc+3 (packed-uint2 mask; i<=fj lanes get 0)
            #pragma unroll
            for (int mi = 1; mi <= 3; ++mi) {
                int i = fjc + mi;
                int zr_i = flip ? (31 - i) : i;
                floatx4 zi4 = *(const floatx4*)(sh_zt + zr_i * 68 + 4 * fg);
                uint2 du = *(const uint2*)(Dh + i * D_BI + fj * D_PJ + 4 * fg);
                bool gt = (i > fj);
                du.x = gt ? du.x : 0u;
                du.y = gt ? du.y : 0u;
                fmix_lo(s4[0], du.x, zi4[0]);
                fmix_hi(s4[1], du.x, zi4[1]);
                fmix_lo(s4[2], du.y, zi4[2]);
                fmix_hi(s4[3], du.y, zi4[3]);
            }
            // unmasked iters i = fjc+4..31 (wave-uniform trip, no selects)
            #pragma unroll 4
            for (int i = fjc + 4; i < 32; ++i) {
                int zr_i = flip ? (31 - i) : i;
                floatx4 zi4 = *(const floatx4*)(sh_zt + zr_i * 68 + 4 * fg);
                uint2 du = *(const uint2*)(Dh + i * D_BI + fj * D_PJ + 4 * fg);
                fmix_lo(s4[0], du.x, zi4[0]);
                fmix_hi(s4[1], du.x, zi4[1]);
                fmix_lo(s4[2], du.y, zi4[2]);
                fmix_hi(s4[3], du.y, zi4[3]);
            }
            // ---- tanh, log-det product, t -> LDS (fp16) ----
            #pragma unroll
            for (int e = 0; e < 4; ++e) {
                float tt = fast_tanh(s4[e]);
                tq4[e] = tt;
                float d1 = half_at(d1q[e], kk), d2 = half_at(d2q[e], kk);
                ld4[e] *= (1.f - tt * tt) * (d1 * d2) + 1.f;
            }
            uint2 tv;
            tv.x = pk2(tq4[0], tq4[1]);
            tv.y = pk2(tq4[2], tq4[3]);
            *(uint2*)(Th + fj * 68 + 4 * fg) = tv;
        }
        // t handoff is cross-wave under the clustered mapping -> barrier
        __syncthreads();
        {
            // ---- dz[p][b] = t[p]*d1 + sum_{j2>p} t[j2][b]*D[p,j2,b] ----
            float dzv4[4];
            #pragma unroll
            for (int e = 0; e < 4; ++e)
                dzv4[e] = tq4[e] * half_at(d1q[e], kk);
            // boundary iters j2 = fjc+1..fjc+3 (packed mask)
            #pragma unroll
            for (int mi = 1; mi <= 3; ++mi) {
                int j2 = fjc + mi;
                uint2 tu = *(const uint2*)(Th + j2 * 68 + 4 * fg);
                uint2 du = *(const uint2*)(Dh + fj * D_BI + j2 * D_PJ + 4 * fg);
                bool gt = (j2 > fj);
                du.x = gt ? du.x : 0u;
                du.y = gt ? du.y : 0u;
                fmix2_ll(dzv4[0], du.x, tu.x);
                fmix2_hh(dzv4[1], du.x, tu.x);
                fmix2_ll(dzv4[2], du.y, tu.y);
                fmix2_hh(dzv4[3], du.y, tu.y);
            }
            // unmasked iters j2 = fjc+4..31
            #pragma unroll 4
            for (int j2 = fjc + 4; j2 < 32; ++j2) {
                uint2 tu = *(const uint2*)(Th + j2 * 68 + 4 * fg);
                uint2 du = *(const uint2*)(Dh + fj * D_BI + j2 * D_PJ + 4 * fg);
                fmix2_ll(dzv4[0], du.x, tu.x);
                fmix2_hh(dzv4[1], du.x, tu.x);
                fmix2_ll(dzv4[2], du.y, tu.y);
                fmix2_hh(dzv4[3], du.y, tu.y);
            }
            // ---- z[zr_j][b] += dz (unique owner per (zr_j, 4-batch group)) ----
            float* zp = sh_zt + zr_j * 68 + 4 * fg;
            floatx4 zc = *(floatx4*)zp;
            #pragma unroll
            for (int e = 0; e < 4; ++e) zc[e] += dzv4[e];
            *(floatx4*)zp = zc;
        }
        __syncthreads();
    }

    // ---- epilogue: write z; reduce log_det over fj via LDS scratch ----
    {
        floatx4 zf = *(const floatx4*)(sh_zt + fj * 68 + 4 * fg);
        #pragma unroll
        for (int e = 0; e < 4; ++e)
            out[(size_t)(bg0 + 4 * fg + e) * ZDIM + fj] = zf[e];

        // D region is dead now; use it as f32 scratch [fj][68] (padded)
        float* lsc = (float*)smem;
        floatx4 lv;
        #pragma unroll
        for (int e = 0; e < 4; ++e)
            lv[e] = __logf(fabsf(ld4[e]));
        *(floatx4*)(lsc + fj * 68 + 4 * fg) = lv;
        __syncthreads();
        if (t < 64) {
            float v = 0.f;
            #pragma unroll 8
            for (int j = 0; j < 32; ++j)
                v += lsc[j * 68 + t];
            out[(size_t)B_TOTAL * ZDIM + bg0 + t] = v;
        }
    }
}

extern "C" void kernel_launch(void* const* d_in, const int* in_sizes, int n_in,
                              void* d_out, int out_size, void* d_ws, size_t ws_size,
                              hipStream_t stream) {
    const float* z0  = (const float*)d_in[0];
    const float* h   = (const float*)d_in[1];
    const float* Wd  = (const float*)d_in[2];
    const float* bd  = (const float*)d_in[3];
    const float* Wd1 = (const float*)d_in[4];
    const float* bd1 = (const float*)d_in[5];
    const float* Wd2 = (const float*)d_in[6];
    const float* bd2 = (const float*)d_in[7];
    const float* Wb  = (const float*)d_in[8];
    const float* bb  = (const float*)d_in[9];
    ushort_t* ws = (ushort_t*)d_ws;
    float* out = (float*)d_out;

    convert_kernel<<<560, 256, 0, stream>>>(Wd, Wd1, Wd2, Wb, ws);

    (void)hipFuncSetAttribute((const void*)sylv_kernel,
                              hipFuncAttributeMaxDynamicSharedMemorySize, LDS_BYTES);
    sylv_kernel<<<B_TOTAL / TB, 512, LDS_BYTES, stream>>>(ws, h, z0, bd, bd1, bd2, bb, out);
}

// Round 13
// 187.992 us; speedup vs baseline: 1.0371x; 1.0371x over previous
//
#include <hip/hip_runtime.h>

typedef unsigned short ushort_t;
typedef unsigned int uint_t;
typedef __attribute__((ext_vector_type(8))) _Float16 f16x8;
typedef __attribute__((ext_vector_type(4))) _Float16 f16x4;
typedef __attribute__((ext_vector_type(2))) _Float16 f16x2;
typedef __attribute__((ext_vector_type(4))) float floatx4;

#define ZDIM 32
#define KDIM 4
#define HDIM 128
#define B_TOTAL 32768
#define TB 64

// ws layout (ushort element offsets): Wd fp16 [k][n][c], Wsm fp16 [m][n][c]
#define WS_WD16 0            // 4*1024*128 = 524288
#define WS_SM16 524288       // 3*128*128 = 49152

// LDS layout: identical to rounds 6/8/10/11 (TB=64, D fp16 [i][j][b64+4pad]).
// Round-25 change vs round-11: CROSS-BARRIER WEIGHT PREFETCH. r11 showed
// VALUBusy 25.5->19.2 with zero duration change => VALU issue off the
// critical path; remaining wall is latency/barrier exposure. The one
// un-hidden latency: 32 global b128 weight loads/thread/k issued mid-GEMM
// with only 2 waves/SIMD. Fix: wpre[4][4] (64 VGPR) holds next-k weights
// for g=0..3, ISSUED AT THE TOP OF THE PRE PHASE -- L2 latency hides
// under pre's LDS/VALU work (compiler can't hoist loads across
// __syncthreads; we do it manually). GEMM(k+1) opens with 64 latency-free
// MFMAs; g=4..7 inline loads hide under them (unroll 2). VGPR 84->~150,
// still 2 waves/SIMD (cap 256). Spill tripwire: WRITE_SIZE must stay
// ~4.2 MB.
#define D_PJ 68              // halves; j stride = 64 batches + 4 pad
#define D_BI 2180            // halves; i stride = 32*68+4
#define SH_D_OFF 0           // 32*2180*2 = 139520 B
#define AUX_PITCH 132
#define AUX_MS (64 * AUX_PITCH)
#define SH_AUX_OFF 0         // float [3][64][132] = 101376 B (pre-loop, aliases D)
#define SH_H_OFF 101376      // half [64][136] = 17408 B (pre-loop, aliases D; ends 118784)
#define SH_ZT_OFF 139520     // float z^T [32][68] = 8704 B (ends 148224)
#define SH_TT_OFF 148224     // half t^T [32][68] = 4352 B (ends 152576)
#define LDS_BYTES 152576     // 1 WG/CU (<= 163840)

__device__ __forceinline__ float fast_tanh(float x) {
    float e = __expf(2.0f * x);
    return 1.0f - 2.0f / (e + 1.0f);
}
__device__ __forceinline__ float f16lo(uint_t v) {
    return (float)__builtin_bit_cast(_Float16, (ushort_t)(v & 0xFFFFu));
}
__device__ __forceinline__ float f16hi(uint_t v) {
    return (float)__builtin_bit_cast(_Float16, (ushort_t)(v >> 16));
}
// pack 2 f32 -> 1 dword of fp16 via v_cvt_pkrtz_f16_f32 (1 VALU op)
__device__ __forceinline__ uint_t pk2(float a, float b) {
    return __builtin_bit_cast(uint_t, __builtin_amdgcn_cvt_pkrtz(a, b));
}
__device__ __forceinline__ ushort4 cvt4(float4 v) {
    uint_t lo = pk2(v.x, v.y), hi = pk2(v.z, v.w);
    ushort4 o;
    o.x = (ushort_t)(lo & 0xFFFFu); o.y = (ushort_t)(lo >> 16);
    o.z = (ushort_t)(hi & 0xFFFFu); o.w = (ushort_t)(hi >> 16);
    return o;
}
// pack 4 floats into 2 dwords of fp16
__device__ __forceinline__ uint2 packq(const float* p) {
    uint2 r;
    r.x = pk2(p[0], p[1]);
    r.y = pk2(p[2], p[3]);
    return r;
}
// runtime-kk variant: kk is wave-uniform -> s_cselect + cndmask, cheap
__device__ __forceinline__ float half_at(uint2 q, int kk) {
    uint_t w = (kk & 2) ? q.y : q.x;
    return (kk & 1) ? f16hi(w) : f16lo(w);
}

// ---- v_fma_mix_f32 helpers: acc += f16(a,half) * b  (b = f32 or f16) ----
__device__ __forceinline__ void fmix_lo(float& acc, uint_t a, float b) {
    asm("v_fma_mix_f32 %0, %1, %2, %0 op_sel_hi:[1,0,0]"
        : "+v"(acc) : "v"(a), "v"(b));
}
__device__ __forceinline__ void fmix_hi(float& acc, uint_t a, float b) {
    asm("v_fma_mix_f32 %0, %1, %2, %0 op_sel:[1,0,0] op_sel_hi:[1,0,0]"
        : "+v"(acc) : "v"(a), "v"(b));
}
__device__ __forceinline__ void fmix2_ll(float& acc, uint_t a, uint_t b) {
    asm("v_fma_mix_f32 %0, %1, %2, %0 op_sel_hi:[1,1,0]"
        : "+v"(acc) : "v"(a), "v"(b));
}
__device__ __forceinline__ void fmix2_hh(float& acc, uint_t a, uint_t b) {
    asm("v_fma_mix_f32 %0, %1, %2, %0 op_sel:[1,1,0] op_sel_hi:[1,1,0]"
        : "+v"(acc) : "v"(a), "v"(b));
}

// ---------------------------------------------------------------------------
// Kernel 1: convert Wd (reordered per-k-slice) and Wd1/Wd2/Wb to fp16.
// ---------------------------------------------------------------------------
__global__ __launch_bounds__(256) void convert_kernel(
    const float* __restrict__ Wd, const float* __restrict__ Wd1,
    const float* __restrict__ Wd2, const float* __restrict__ Wb,
    ushort_t* __restrict__ ws)
{
    int g = blockIdx.x * 256 + threadIdx.x;
    if (g < 131072) {
        int k = g >> 15;            // 32768 float4 per k-slice
        int rem = g & 32767;
        int n = rem >> 5;           // n = i*32+j
        int c4 = rem & 31;
        float4 v = *((const float4*)Wd + (size_t)(4 * n + k) * 32 + c4);
        ((ushort4*)(ws + WS_WD16))[g] = cvt4(v);
    } else {
        int s = g - 131072;         // [0, 12288)
        const float* src = (s < 4096) ? Wd1 : ((s < 8192) ? Wd2 : Wb);
        int r = s & 4095;
        float4 v = ((const float4*)src)[r];
        ((ushort4*)(ws + WS_SM16))[s] = cvt4(v);
    }
}

// ---------------------------------------------------------------------------
// Kernel 2: fused fp16 encoder GEMMs + K-step flow. TB=64 batches/WG,
// 512 threads (8 waves), 1 WG/CU, 512 WGs (2 slots/CU). Flow mapping:
// fj = t>>4 (wave-clustered), fg = t&15. 3 barriers per k.
// ---------------------------------------------------------------------------
__global__ __launch_bounds__(512, 2) void sylv_kernel(
    const ushort_t* __restrict__ wsb,
    const float* __restrict__ hglob,
    const float* __restrict__ z0,
    const float* __restrict__ bd,
    const float* __restrict__ bd1,
    const float* __restrict__ bd2,
    const float* __restrict__ bb,
    float* __restrict__ out)
{
    extern __shared__ char smem[];
    _Float16* Dh     = (_Float16*)(smem + SH_D_OFF);
    float*    sh_aux = (float*)(smem + SH_AUX_OFF);
    _Float16* sh_h   = (_Float16*)(smem + SH_H_OFF);
    float*    sh_zt  = (float*)(smem + SH_ZT_OFF);
    _Float16* Th     = (_Float16*)(smem + SH_TT_OFF);

    const int t   = threadIdx.x;
    const int bg0 = blockIdx.x * TB;
    const int lane = t & 63, w = t >> 6;    // w = 0..7 = GEMM column group
    const int l15 = lane & 15, l4 = lane >> 4;
    // flow mapping: fj = row/col index (wave-clustered), fg = 4-batch group
    const int fj = t >> 4;          // 0..31; wave w covers fj in [4w, 4w+3]
    const int fg = t & 15;          // 0..15
    const int fjc = w * 4;          // wave-uniform cluster base

    // ---- stage h (fp32 -> fp16 in LDS) and z0 transposed ----
    {
        const float4* hsrc = (const float4*)(hglob + (size_t)bg0 * HDIM);
        #pragma unroll
        for (int it = 0; it < 4; ++it) {
            int c = t + it * 512;       // 2048 float4 chunks (64 rows x 32)
            int row = c >> 5, col4 = c & 31;
            float4 v = hsrc[c];
            *(ushort4*)((ushort_t*)sh_h + row * 136 + col4 * 4) = cvt4(v);
        }
        int zb = t >> 3;                // 0..63 (batch)
        int zi0 = (t & 7) * 4;          // i index
        float4 zv = *(const float4*)(z0 + (size_t)(bg0 + zb) * ZDIM + zi0);
        sh_zt[(zi0 + 0) * 68 + zb] = zv.x;
        sh_zt[(zi0 + 1) * 68 + zb] = zv.y;
        sh_zt[(zi0 + 2) * 68 + zb] = zv.z;
        sh_zt[(zi0 + 3) * 68 + zb] = zv.w;
    }
    __syncthreads();

    // ---- A fragments: FOUR 16-row tiles (rows 0..63), same for all waves ----
    f16x8 ah[4][4];
    #pragma unroll
    for (int mt = 0; mt < 4; ++mt)
        #pragma unroll
        for (int kc = 0; kc < 4; ++kc)
            ah[mt][kc] = *(const f16x8*)(sh_h + (mt * 16 + l15) * 136 + kc * 32 + l4 * 8);

    // ---- small GEMMs (fp16): d1, d2, bpre -> aux[m][batch][n] ----
    #pragma unroll 1
    for (int pi = 0; pi < 3; ++pi) {
        int p = w * 3 + pi;             // [0,24)
        int m_i = p >> 3, nt = p & 7, n = nt * 16 + l15;
        const _Float16* wp = (const _Float16*)(wsb + WS_SM16) + (size_t)(m_i * 128 + n) * 128 + l4 * 8;
        const float* bv = (m_i == 0) ? bd1 : ((m_i == 1) ? bd2 : bb);
        float bias = bv[n];
        floatx4 a[4];
        #pragma unroll
        for (int mt = 0; mt < 4; ++mt)
            a[mt] = (floatx4){bias, bias, bias, bias};
        #pragma unroll
        for (int kc = 0; kc < 4; ++kc) {
            f16x8 bh = *(const f16x8*)(wp + kc * 32);
            #pragma unroll
            for (int mt = 0; mt < 4; ++mt)
                a[mt] = __builtin_amdgcn_mfma_f32_16x16x32_f16(ah[mt][kc], bh, a[mt], 0, 0, 0);
        }
        float* ap = sh_aux + m_i * AUX_MS + n;
        #pragma unroll
        for (int mt = 0; mt < 4; ++mt) {
            #pragma unroll
            for (int r = 0; r < 4; ++r) {
                float v0 = a[mt][r];
                if (m_i < 2) v0 = fast_tanh(v0);
                ap[(mt * 16 + l4 * 4 + r) * AUX_PITCH] = v0;
            }
        }
    }
    __syncthreads();

    // ---- pack aux for (fj, 4 batches) x 4 k into fp16 regs ----
    uint2 d1q[4], d2q[4], bpq[4];
    {
        #pragma unroll
        for (int e = 0; e < 4; ++e) {
            const float* base = sh_aux + (4 * fg + e) * AUX_PITCH + 4 * fj;
            d1q[e] = packq(base + 0 * AUX_MS);
            d2q[e] = packq(base + 1 * AUX_MS);
            bpq[e] = packq(base + 2 * AUX_MS);
        }
    }
    __syncthreads();

    float ld4[4] = {1.f, 1.f, 1.f, 1.f};    // product of dj per (row, batch)

    // ---- cross-barrier weight prefetch buffer: g=0..3 of current k ----
    const _Float16* wd_base = (const _Float16*)(wsb + WS_WD16);
    f16x8 wpre[4][4];
    {
        // prologue: prefetch k=0, g=0..3
        const _Float16* w00 = wd_base + (size_t)(w * 128 + l15) * 128 + l4 * 8;
        #pragma unroll
        for (int g = 0; g < 4; ++g)
            #pragma unroll
            for (int kc = 0; kc < 4; ++kc)
                wpre[g][kc] = *(const f16x8*)(w00 + (size_t)g * 2048 + kc * 32);
    }

    #pragma unroll 1
    for (int kk = 0; kk < KDIM; ++kk) {
        // ---- GEMM: D_k[b][n] = h@Wd_k^T + bd; write [i][j][b] as b64 ----
        const _Float16* wdk = wd_base + (size_t)kk * 131072;
        // g = 0..3: weights already in registers (prefetched during flow(k-1))
        #pragma unroll
        for (int g = 0; g < 4; ++g) {
            int nc = w * 128 + g * 16 + l15;
            float bias0 = bd[4 * nc + kk];
            floatx4 a[4];
            #pragma unroll
            for (int mt = 0; mt < 4; ++mt)
                a[mt] = (floatx4){bias0, bias0, bias0, bias0};
            #pragma unroll
            for (int kc = 0; kc < 4; ++kc) {
                #pragma unroll
                for (int mt = 0; mt < 4; ++mt)
                    a[mt] = __builtin_amdgcn_mfma_f32_16x16x32_f16(ah[mt][kc], wpre[g][kc], a[mt], 0, 0, 0);
            }
            int ii = nc >> 5, jj = nc & 31;
            int base = ii * D_BI + jj * D_PJ;       // halves
            #pragma unroll
            for (int mt = 0; mt < 4; ++mt) {
                uint2 ov;
                ov.x = pk2(a[mt][0], a[mt][1]);
                ov.y = pk2(a[mt][2], a[mt][3]);
                *(uint2*)(Dh + base + mt * 16 + l4 * 4) = ov;
            }
        }
        // g = 4..7: inline loads, hidden under g=0..3 MFMAs (independent)
        #pragma unroll 2
        for (int g = 4; g < 8; ++g) {
            int nc = w * 128 + g * 16 + l15;
            const _Float16* w0 = wdk + (size_t)nc * 128 + l4 * 8;
            float bias0 = bd[4 * nc + kk];
            floatx4 a[4];
            #pragma unroll
            for (int mt = 0; mt < 4; ++mt)
                a[mt] = (floatx4){bias0, bias0, bias0, bias0};
            #pragma unroll
            for (int kc = 0; kc < 4; ++kc) {
                f16x8 b0 = *(const f16x8*)(w0 + kc * 32);
                #pragma unroll
                for (int mt = 0; mt < 4; ++mt)
                    a[mt] = __builtin_amdgcn_mfma_f32_16x16x32_f16(ah[mt][kc], b0, a[mt], 0, 0, 0);
            }
            int ii = nc >> 5, jj = nc & 31;
            int base = ii * D_BI + jj * D_PJ;       // halves
            #pragma unroll
            for (int mt = 0; mt < 4; ++mt) {
                uint2 ov;
                ov.x = pk2(a[mt][0], a[mt][1]);
                ov.y = pk2(a[mt][2], a[mt][3]);
                *(uint2*)(Dh + base + mt * 16 + l4 * 4) = ov;
            }
        }
        __syncthreads();

        const bool flip = (kk & 1) != 0;
        const int zr_j = flip ? (31 - fj) : fj;
        float tq4[4];
        {
            // ---- prefetch next k's g=0..3 weights: latency hides under pre ----
            if (kk + 1 < KDIM) {
                const _Float16* wn = wd_base + (size_t)(kk + 1) * 131072
                                   + (size_t)(w * 128 + l15) * 128 + l4 * 8;
                #pragma unroll
                for (int g = 0; g < 4; ++g)
                    #pragma unroll
                    for (int kc = 0; kc < 4; ++kc)
                        wpre[g][kc] = *(const f16x8*)(wn + (size_t)g * 2048 + kc * 32);
            }

            // ---- pre[j][b] = bp + z_per[j]*d2 + sum_{i>j} z_per[i]*D[i,j,b] ----
            float s4[4];
            {
                floatx4 zj = *(const floatx4*)(sh_zt + zr_j * 68 + 4 * fg);
                #pragma unroll
                for (int e = 0; e < 4; ++e)
                    s4[e] = half_at(bpq[e], kk) + zj[e] * half_at(d2q[e], kk);
            }
            // boundary iters i = fjc+1..fjc+3 (packed-uint2 mask; i<=fj lanes get 0)
            #pragma unroll
            for (int mi = 1; mi <= 3; ++mi) {
                int i = fjc + mi;
                int zr_i = flip ? (31 - i) : i;
                floatx4 zi4 = *(const floatx4*)(sh_zt + zr_i * 68 + 4 * fg);
                uint2 du = *(const uint2*)(Dh + i * D_BI + fj * D_PJ + 4 * fg);
                bool gt = (i > fj);
                du.x = gt ? du.x : 0u;
                du.y = gt ? du.y : 0u;
                fmix_lo(s4[0], du.x, zi4[0]);
                fmix_hi(s4[1], du.x, zi4[1]);
                fmix_lo(s4[2], du.y, zi4[2]);
                fmix_hi(s4[3], du.y, zi4[3]);
            }
            // unmasked iters i = fjc+4..31 (wave-uniform trip, no selects)
            #pragma unroll 4
            for (int i = fjc + 4; i < 32; ++i) {
                int zr_i = flip ? (31 - i) : i;
                floatx4 zi4 = *(const floatx4*)(sh_zt + zr_i * 68 + 4 * fg);
                uint2 du = *(const uint2*)(Dh + i * D_BI + fj * D_PJ + 4 * fg);
                fmix_lo(s4[0], du.x, zi4[0]);
                fmix_hi(s4[1], du.x, zi4[1]);
                fmix_lo(s4[2], du.y, zi4[2]);
                fmix_hi(s4[3], du.y, zi4[3]);
            }
            // ---- tanh, log-det product, t -> LDS (fp16) ----
            #pragma unroll
            for (int e = 0; e < 4; ++e) {
                float tt = fast_tanh(s4[e]);
                tq4[e] = tt;
                float d1 = half_at(d1q[e], kk), d2 = half_at(d2q[e], kk);
                ld4[e] *= (1.f - tt * tt) * (d1 * d2) + 1.f;
            }
            uint2 tv;
            tv.x = pk2(tq4[0], tq4[1]);
            tv.y = pk2(tq4[2], tq4[3]);
            *(uint2*)(Th + fj * 68 + 4 * fg) = tv;
        }
        // t handoff is cross-wave under the clustered mapping -> barrier
        __syncthreads();
        {
            // ---- dz[p][b] = t[p]*d1 + sum_{j2>p} t[j2][b]*D[p,j2,b] ----
            float dzv4[4];
            #pragma unroll
            for (int e = 0; e < 4; ++e)
                dzv4[e] = tq4[e] * half_at(d1q[e], kk);
            // boundary iters j2 = fjc+1..fjc+3 (packed mask)
            #pragma unroll
            for (int mi = 1; mi <= 3; ++mi) {
                int j2 = fjc + mi;
                uint2 tu = *(const uint2*)(Th + j2 * 68 + 4 * fg);
                uint2 du = *(const uint2*)(Dh + fj * D_BI + j2 * D_PJ + 4 * fg);
                bool gt = (j2 > fj);
                du.x = gt ? du.x : 0u;
                du.y = gt ? du.y : 0u;
                fmix2_ll(dzv4[0], du.x, tu.x);
                fmix2_hh(dzv4[1], du.x, tu.x);
                fmix2_ll(dzv4[2], du.y, tu.y);
                fmix2_hh(dzv4[3], du.y, tu.y);
            }
            // unmasked iters j2 = fjc+4..31
            #pragma unroll 4
            for (int j2 = fjc + 4; j2 < 32; ++j2) {
                uint2 tu = *(const uint2*)(Th + j2 * 68 + 4 * fg);
                uint2 du = *(const uint2*)(Dh + fj * D_BI + j2 * D_PJ + 4 * fg);
                fmix2_ll(dzv4[0], du.x, tu.x);
                fmix2_hh(dzv4[1], du.x, tu.x);
                fmix2_ll(dzv4[2], du.y, tu.y);
                fmix2_hh(dzv4[3], du.y, tu.y);
            }
            // ---- z[zr_j][b] += dz (unique owner per (zr_j, 4-batch group)) ----
            float* zp = sh_zt + zr_j * 68 + 4 * fg;
            floatx4 zc = *(floatx4*)zp;
            #pragma unroll
            for (int e = 0; e < 4; ++e) zc[e] += dzv4[e];
            *(floatx4*)zp = zc;
        }
        __syncthreads();
    }

    // ---- epilogue: write z; reduce log_det over fj via LDS scratch ----
    {
        floatx4 zf = *(const floatx4*)(sh_zt + fj * 68 + 4 * fg);
        #pragma unroll
        for (int e = 0; e < 4; ++e)
            out[(size_t)(bg0 + 4 * fg + e) * ZDIM + fj] = zf[e];

        // D region is dead now; use it as f32 scratch [fj][68] (padded)
        float* lsc = (float*)smem;
        floatx4 lv;
        #pragma unroll
        for (int e = 0; e < 4; ++e)
            lv[e] = __logf(fabsf(ld4[e]));
        *(floatx4*)(lsc + fj * 68 + 4 * fg) = lv;
        __syncthreads();
        if (t < 64) {
            float v = 0.f;
            #pragma unroll 8
            for (int j = 0; j < 32; ++j)
                v += lsc[j * 68 + t];
            out[(size_t)B_TOTAL * ZDIM + bg0 + t] = v;
        }
    }
}

extern "C" void kernel_launch(void* const* d_in, const int* in_sizes, int n_in,
                              void* d_out, int out_size, void* d_ws, size_t ws_size,
                              hipStream_t stream) {
    const float* z0  = (const float*)d_in[0];
    const float* h   = (const float*)d_in[1];
    const float* Wd  = (const float*)d_in[2];
    const float* bd  = (const float*)d_in[3];
    const float* Wd1 = (const float*)d_in[4];
    const float* bd1 = (const float*)d_in[5];
    const float* Wd2 = (const float*)d_in[6];
    const float* bd2 = (const float*)d_in[7];
    const float* Wb  = (const float*)d_in[8];
    const float* bb  = (const float*)d_in[9];
    ushort_t* ws = (ushort_t*)d_ws;
    float* out = (float*)d_out;

    convert_kernel<<<560, 256, 0, stream>>>(Wd, Wd1, Wd2, Wb, ws);

    (void)hipFuncSetAttribute((const void*)sylv_kernel,
                              hipFuncAttributeMaxDynamicSharedMemorySize, LDS_BYTES);
    sylv_kernel<<<B_TOTAL / TB, 512, LDS_BYTES, stream>>>(ws, h, z0, bd, bd1, bd2, bb, out);
}